// Round 1
// baseline (30.138 us; speedup 1.0000x reference)
//
#include <hip/hip_runtime.h>

// NeuralPonds: flavor = int(abs(np-pairwise-sum over d_model)) % 10000,
// out[token] = tables[pond[token], flavor]  (row of 1024 f32)
//
// Correctness hinges on reproducing numpy's pairwise summation bit-exactly:
// n=1024 -> 8 contiguous blocks of 128; each block = 8 accumulators
// r[j] = a[j] + a[j+8] + ... + a[j+120] (sequential, left-to-right);
// combine ((r0+r1)+(r2+r3))+((r4+r5)+(r6+r7)); blocks combined by the same
// balanced binary tree. This is exactly: lane l = 8*b+j owns one chain,
// then a 64-lane shfl_xor butterfly (masks 1..32). FP add is commutative,
// so both butterfly partners hold bitwise-identical sums at every level.

#define POND_MOD 10000
#define D_MODEL 1024

__global__ __launch_bounds__(256) void NeuralPonds_54898271977921_kernel(
    const float* __restrict__ ctx,      // [ntok, 1024]
    const int*   __restrict__ pond,     // [ntok]
    const float* __restrict__ tables,   // [10, 10000, 1024]
    float*       __restrict__ out,      // [ntok, 1024]
    int ntok)
{
    const int lane  = threadIdx.x & 63;
    const int wid   = threadIdx.x >> 6;          // wave within block (0..3)
    const int token = blockIdx.x * 4 + wid;      // one wave per token
    if (token >= ntok) return;

    const float* row = ctx + (size_t)token * D_MODEL;

    // lane l: block b = l>>3 (128-elem chunk), accumulator j = l&7
    const int b = lane >> 3;
    const int j = lane & 7;
    const float* p = row + b * 128 + j;

    // sequential chain, numpy order: r = a[j]; r += a[j+8]; ... (16 terms)
    float r = p[0];
    #pragma unroll
    for (int k = 1; k < 16; ++k) {
        r += p[8 * k];
    }

    // balanced-binary-tree combine across 64 lanes == numpy pairwise tree
    #pragma unroll
    for (int m = 1; m < 64; m <<= 1) {
        r += __shfl_xor(r, m, 64);
    }

    const int flavor = ((int)fabsf(r)) % POND_MOD;
    const int pd     = pond[token];

    const float4* src = (const float4*)(tables + ((size_t)pd * POND_MOD + flavor) * D_MODEL);
    float4*       dst = (float4*)(out + (size_t)token * D_MODEL);

    // 1024 floats = 256 float4; 64 lanes x 4 iterations, fully coalesced
    #pragma unroll
    for (int k = 0; k < 4; ++k) {
        dst[k * 64 + lane] = src[k * 64 + lane];
    }
}

extern "C" void kernel_launch(void* const* d_in, const int* in_sizes, int n_in,
                              void* d_out, int out_size, void* d_ws, size_t ws_size,
                              hipStream_t stream) {
    const float* ctx    = (const float*)d_in[0];   // context_vector [4,4096,1024] f32
    const int*   pond   = (const int*)d_in[1];     // pond_assignments [4,4096] i32
    const float* tables = (const float*)d_in[2];   // tables [10,10000,1024] f32
    float*       out    = (float*)d_out;           // [4,4096,1024] f32

    const int ntok = in_sizes[1];                  // 16384 tokens
    const int blocks = (ntok + 3) / 4;             // 4 waves (tokens) per block

    NeuralPonds_54898271977921_kernel<<<blocks, 256, 0, stream>>>(
        ctx, pond, tables, out, ntok);
}

// Round 2
// 30.036 us; speedup vs baseline: 1.0034x; 1.0034x over previous
//
#include <hip/hip_runtime.h>

// NeuralPonds: flavor = int(abs(np-pairwise-sum over d_model)) % 10000,
// out[token] = tables[pond[token], flavor]  (row of 1024 f32)
//
// Bit-exact numpy pairwise sum (verified on HW in R1, absmax 0.0):
// 64 sequential chains r[b][j] = sum_k a[b*128 + j + 8k] (k=0..15, numpy order)
// combined by a balanced binary tree == 64-lane shfl_xor butterfly.
//
// R2 change: ctx is read with coalesced float4 loads (full 128B lines per
// wave-instruction) and transposed through LDS (per-wave region, 128->132
// float padding => strided read is 2-way bank aliasing = free per m136),
// replacing 16 scalar strided global loads per lane.

#define POND_MOD 10000
#define D_MODEL  1024
#define PADDED   132            // 128 + 4 pad floats per 128-elem sub-block
#define WAVE_LDS (8 * PADDED)   // 1056 floats per wave

__global__ __launch_bounds__(256) void NeuralPonds_54898271977921_kernel(
    const float* __restrict__ ctx,      // [ntok, 1024]
    const int*   __restrict__ pond,     // [ntok]
    const float* __restrict__ tables,   // [10, 10000, 1024]
    float*       __restrict__ out,      // [ntok, 1024]
    int ntok)
{
    __shared__ float lds[4 * WAVE_LDS];

    const int lane  = threadIdx.x & 63;
    const int wid   = threadIdx.x >> 6;           // wave within block (0..3)
    const int token = blockIdx.x * 4 + wid;       // one wave per token
    const bool valid = token < ntok;
    const int  tok_safe = valid ? token : 0;

    // --- coalesced load of the 4KB ctx row: 4 x float4 per lane ---
    const float4* row4 = (const float4*)(ctx + (size_t)tok_safe * D_MODEL);
    int pd = pond[tok_safe];                      // prefetch pond early
    float4 v[4];
    #pragma unroll
    for (int t = 0; t < 4; ++t)
        v[t] = row4[t * 64 + lane];

    // --- transpose into padded LDS ---
    // global element e = 256t + 4l + s  ->  lds[block(e>>7)][local(e&127)]
    // padded addr = (2t + (l>>5))*132 + 4*(l&31) + s
    float* w = lds + wid * WAVE_LDS;
    const int l31 = lane & 31;
    const int hb  = lane >> 5;
    #pragma unroll
    for (int t = 0; t < 4; ++t)
        *(float4*)(w + (2 * t + hb) * PADDED + 4 * l31) = v[t];

    __syncthreads();

    // --- numpy-order chain: lane l = 8b + j sums a[b*128 + j + 8k] ---
    const int b = lane >> 3;
    const int j = lane & 7;
    const float* rp = w + b * PADDED + j;
    float r = rp[0];
    #pragma unroll
    for (int k = 1; k < 16; ++k)
        r += rp[8 * k];

    // balanced-binary-tree combine across 64 lanes == numpy pairwise tree
    #pragma unroll
    for (int m = 1; m < 64; m <<= 1)
        r += __shfl_xor(r, m, 64);

    // --- gather + store, fully coalesced float4 ---
    if (valid) {
        const int flavor = ((int)fabsf(r)) % POND_MOD;
        const float4* src = (const float4*)(tables + ((size_t)pd * POND_MOD + flavor) * D_MODEL);
        float4*       dst = (float4*)(out + (size_t)token * D_MODEL);
        #pragma unroll
        for (int k = 0; k < 4; ++k)
            dst[k * 64 + lane] = src[k * 64 + lane];
    }
}

extern "C" void kernel_launch(void* const* d_in, const int* in_sizes, int n_in,
                              void* d_out, int out_size, void* d_ws, size_t ws_size,
                              hipStream_t stream) {
    const float* ctx    = (const float*)d_in[0];   // context_vector [4,4096,1024] f32
    const int*   pond   = (const int*)d_in[1];     // pond_assignments [4,4096] i32
    const float* tables = (const float*)d_in[2];   // tables [10,10000,1024] f32
    float*       out    = (float*)d_out;           // [4,4096,1024] f32

    const int ntok = in_sizes[1];                  // 16384 tokens
    const int blocks = (ntok + 3) / 4;             // 4 waves (tokens) per block

    NeuralPonds_54898271977921_kernel<<<blocks, 256, 0, stream>>>(
        ctx, pond, tables, out, ntok);
}

// Round 3
// 27.801 us; speedup vs baseline: 1.0841x; 1.0804x over previous
//
#include <hip/hip_runtime.h>

// NeuralPonds: flavor = int(abs(np-pairwise-sum over d_model)) % 10000,
// out[token] = tables[pond[token], flavor]  (row of 1024 f32)
//
// Bit-exact numpy pairwise sum (verified on HW, absmax 0.0): 64 sequential
// chains r[b][j] = sum_k a[b*128 + j + 8k] combined by a balanced binary
// tree == 64-lane shfl_xor butterfly.
//
// R3: two-kernel phase split. k1 = pure-read reduce -> combined index in
// d_ws. k2 = gather + pure nontemporal write (table rows are ~1300 unique
// 4KB rows => L2/L3-resident). Each kernel is a homogeneous memory stream.

#define POND_MOD 10000
#define D_MODEL  1024
#define PADDED   132            // 128 + 4 pad floats per 128-elem sub-block
#define WAVE_LDS (8 * PADDED)

typedef float f32x4 __attribute__((ext_vector_type(4)));

__global__ __launch_bounds__(256) void np_flavor_kernel(
    const float* __restrict__ ctx,      // [ntok, 1024]
    const int*   __restrict__ pond,     // [ntok]
    int*         __restrict__ idxbuf,   // [ntok] combined pond*10000+flavor
    int ntok)
{
    __shared__ float lds[4 * WAVE_LDS];

    const int lane  = threadIdx.x & 63;
    const int wid   = threadIdx.x >> 6;
    const int token = blockIdx.x * 4 + wid;       // one wave per token
    const bool valid = token < ntok;
    const int  tok_safe = valid ? token : 0;

    // coalesced nontemporal load of the 4KB ctx row (never reused)
    const f32x4* row4 = (const f32x4*)(ctx + (size_t)tok_safe * D_MODEL);
    int pd = pond[tok_safe];
    f32x4 v[4];
    #pragma unroll
    for (int t = 0; t < 4; ++t)
        v[t] = __builtin_nontemporal_load(&row4[t * 64 + lane]);

    // transpose into padded LDS (2-way bank aliasing on read = free)
    float* w = lds + wid * WAVE_LDS;
    const int l31 = lane & 31;
    const int hb  = lane >> 5;
    #pragma unroll
    for (int t = 0; t < 4; ++t)
        *(f32x4*)(w + (2 * t + hb) * PADDED + 4 * l31) = v[t];

    __syncthreads();

    // numpy-order chain: lane l = 8b + j sums a[b*128 + j + 8k]
    const int b = lane >> 3;
    const int j = lane & 7;
    const float* rp = w + b * PADDED + j;
    float r = rp[0];
    #pragma unroll
    for (int k = 1; k < 16; ++k)
        r += rp[8 * k];

    // balanced-binary-tree combine == numpy pairwise tree
    #pragma unroll
    for (int m = 1; m < 64; m <<= 1)
        r += __shfl_xor(r, m, 64);

    if (valid && lane == 0) {
        const int flavor = ((int)fabsf(r)) % POND_MOD;
        idxbuf[token] = pd * POND_MOD + flavor;
    }
}

__global__ __launch_bounds__(256) void np_gather_kernel(
    const float* __restrict__ tables,   // [10*10000, 1024]
    const int*   __restrict__ idxbuf,   // [ntok]
    float*       __restrict__ out,      // [ntok, 1024]
    int ntok)
{
    const int lane  = threadIdx.x & 63;
    const int wid   = threadIdx.x >> 6;
    const int token = blockIdx.x * 4 + wid;
    if (token >= ntok) return;

    const int idx = __builtin_amdgcn_readfirstlane(idxbuf[token]);
    const f32x4* src = (const f32x4*)(tables + (size_t)idx * D_MODEL);
    f32x4*       dst = (f32x4*)(out + (size_t)token * D_MODEL);

    #pragma unroll
    for (int k = 0; k < 4; ++k) {
        f32x4 v = src[k * 64 + lane];                     // cached (hot rows)
        __builtin_nontemporal_store(v, &dst[k * 64 + lane]); // pure stream out
    }
}

// fallback single kernel (ws too small) — R1/R2 verified path
__global__ __launch_bounds__(256) void np_fused_kernel(
    const float* __restrict__ ctx, const int* __restrict__ pond,
    const float* __restrict__ tables, float* __restrict__ out, int ntok)
{
    const int lane  = threadIdx.x & 63;
    const int wid   = threadIdx.x >> 6;
    const int token = blockIdx.x * 4 + wid;
    if (token >= ntok) return;

    const float* row = ctx + (size_t)token * D_MODEL;
    const int b = lane >> 3, j = lane & 7;
    const float* p = row + b * 128 + j;
    float r = p[0];
    #pragma unroll
    for (int k = 1; k < 16; ++k) r += p[8 * k];
    #pragma unroll
    for (int m = 1; m < 64; m <<= 1) r += __shfl_xor(r, m, 64);

    const int flavor = ((int)fabsf(r)) % POND_MOD;
    const int pd = pond[token];
    const float4* src = (const float4*)(tables + ((size_t)pd * POND_MOD + flavor) * D_MODEL);
    float4*       dst = (float4*)(out + (size_t)token * D_MODEL);
    #pragma unroll
    for (int k = 0; k < 4; ++k) dst[k * 64 + lane] = src[k * 64 + lane];
}

extern "C" void kernel_launch(void* const* d_in, const int* in_sizes, int n_in,
                              void* d_out, int out_size, void* d_ws, size_t ws_size,
                              hipStream_t stream) {
    const float* ctx    = (const float*)d_in[0];
    const int*   pond   = (const int*)d_in[1];
    const float* tables = (const float*)d_in[2];
    float*       out    = (float*)d_out;

    const int ntok   = in_sizes[1];               // 16384 tokens
    const int blocks = (ntok + 3) / 4;

    if (ws_size >= (size_t)ntok * sizeof(int)) {
        int* idxbuf = (int*)d_ws;
        np_flavor_kernel<<<blocks, 256, 0, stream>>>(ctx, pond, idxbuf, ntok);
        np_gather_kernel<<<blocks, 256, 0, stream>>>(tables, idxbuf, out, ntok);
    } else {
        np_fused_kernel<<<blocks, 256, 0, stream>>>(ctx, pond, tables, out, ntok);
    }
}